// Round 1
// baseline (6775.892 us; speedup 1.0000x reference)
//
#include <hip/hip_runtime.h>

// Problem constants
#define PM    10000   // patches / mesh nodes
#define NP_N  50      // nodes per patch
#define EP_N  200     // edges per patch
#define IN_C  64
#define H1_C  256
#define C2_C  64
#define RD_C  128
#define EM_N  160000  // mesh edges
#define OUT_C 16
#define EPSV  1e-5f
#define FPAD  68      // padded row stride for 64-channel LDS tiles

// workspace layout (float offsets)
#define OFF_EMB   0          // [PM][128] row-major
#define OFF_DEGO  1280000    // [PM]
#define OFF_DEGI  1290000    // [PM]
#define OFF_AGG1  1300000    // [128][PM] transposed
#define OFF_H     2580000    // [256][PM] transposed (X1 -> h in place)
#define OFF_AGG2  5140000    // [256][PM] transposed
#define OFF_X2    1300000    // [256][PM] overlays agg1+first half of H (both dead)
#define OFF_STATS 7700000    // sums1[256] sumsq1[256] sums2[256] sumsq2[256] ro[512]

// ---------------------------------------------------------------------------
// Patch embedder: one block per patch. lane = node (50 active of 64).
// Fuses: conv1, GEMM1(@W1), graph_norm+lrelu, GEMM(@W2) [commuted before conv2],
// conv2, graph_norm+lrelu, readouts r0/r1/r2, @We, InstanceNorm+lrelu.
// ---------------------------------------------------------------------------
__global__ __launch_bounds__(256) void patch_kernel(
    const float* __restrict__ feats, const int* __restrict__ esrc,
    const int* __restrict__ edst, const float* __restrict__ eew,
    const float* __restrict__ W1, const float* __restrict__ g1,
    const float* __restrict__ b1, const float* __restrict__ W2,
    const float* __restrict__ g2, const float* __restrict__ b2,
    const float* __restrict__ We, float* __restrict__ embout)
{
    __shared__ float s_feat[64 * FPAD];   // feat -> later Z
    __shared__ float s_gc[64 * FPAD];     // conv1 agg -> later conv2 agg
    __shared__ int   s_src[EP_N];
    __shared__ int   s_dst[EP_N];
    __shared__ float s_ew[EP_N];
    __shared__ float s_deg[128];          // degO[0:64], degI[64:128]
    __shared__ float s_rs[128];           // rsqrt(max(deg,1))
    __shared__ float s_r[384];            // r0|r1|r2
    __shared__ float s_red[8];

    const int tid  = threadIdx.x;
    const int p    = blockIdx.x;
    const int lane = tid & 63;
    const int wave = tid >> 6;

    for (int i = tid; i < 64 * FPAD; i += 256) { s_feat[i] = 0.f; s_gc[i] = 0.f; }
    if (tid < 128) s_deg[tid] = 0.f;
    if (tid < EP_N) {
        s_src[tid] = esrc[p * EP_N + tid];
        s_dst[tid] = edst[p * EP_N + tid];
        s_ew[tid]  = eew[p * EP_N + tid];
    }
    __syncthreads();
    if (tid < EP_N) {
        atomicAdd(&s_deg[s_src[tid]], 1.f);
        atomicAdd(&s_deg[64 + s_dst[tid]], 1.f);
    }
    // load feat [50][64] as float4, padded rows
    for (int i = tid; i < 800; i += 256) {
        int n = i >> 4, c4 = (i & 15) << 2;
        float4 v = *(const float4*)&feats[(size_t)p * (NP_N * IN_C) + n * IN_C + c4];
        *(float4*)&s_feat[n * FPAD + c4] = v;
    }
    __syncthreads();
    if (tid < 128) s_rs[tid] = rsqrtf(fmaxf(s_deg[tid], 1.f));
    __syncthreads();
    // r0 = feat.mean(0)
    if (tid < IN_C) {
        float s = 0.f;
        for (int n = 0; n < NP_N; ++n) s += s_feat[n * FPAD + tid];
        s_r[tid] = s * (1.f / NP_N);
    }
    __syncthreads();
    // scale feat rows by rsqrt(deg_out)
    for (int i = tid; i < 800; i += 256) {
        int n = i >> 4, c4 = (i & 15) << 2;
        float sc = s_rs[n];
        float4 v = *(float4*)&s_feat[n * FPAD + c4];
        v.x *= sc; v.y *= sc; v.z *= sc; v.w *= sc;
        *(float4*)&s_feat[n * FPAD + c4] = v;
    }
    __syncthreads();
    // conv1: gather over edges into s_gc
    for (int i = tid; i < EP_N * 16; i += 256) {
        int e = i >> 4, c4 = (i & 15) << 2;
        int s = s_src[e], d = s_dst[e];
        float w = s_ew[e];
        float4 v = *(const float4*)&s_feat[s * FPAD + c4];
        atomicAdd(&s_gc[d * FPAD + c4 + 0], v.x * w);
        atomicAdd(&s_gc[d * FPAD + c4 + 1], v.y * w);
        atomicAdd(&s_gc[d * FPAD + c4 + 2], v.z * w);
        atomicAdd(&s_gc[d * FPAD + c4 + 3], v.w * w);
    }
    __syncthreads();

    // fused: X1 = rsI * (gc1 @ W1); graph_norm+lrelu; r1; Z += h1 @ W2
    const int n = lane;
    const float rsI = s_rs[64 + n];
    float zacc[C2_C];
    #pragma unroll
    for (int k = 0; k < C2_C; ++k) zacc[k] = 0.f;

    for (int chunk = 0; chunk < 4; ++chunk) {
        const int j0 = __builtin_amdgcn_readfirstlane(wave * 64 + chunk * 16);
        float a[16];
        #pragma unroll
        for (int jj = 0; jj < 16; ++jj) a[jj] = 0.f;
        for (int c4 = 0; c4 < 16; ++c4) {
            float4 gv = *(const float4*)&s_gc[n * FPAD + c4 * 4];
            const float* wp0 = W1 + (c4 * 4 + 0) * H1_C + j0;
            const float* wp1 = W1 + (c4 * 4 + 1) * H1_C + j0;
            const float* wp2 = W1 + (c4 * 4 + 2) * H1_C + j0;
            const float* wp3 = W1 + (c4 * 4 + 3) * H1_C + j0;
            #pragma unroll
            for (int jj = 0; jj < 16; ++jj) {
                a[jj] = fmaf(gv.x, wp0[jj], a[jj]);
                a[jj] = fmaf(gv.y, wp1[jj], a[jj]);
                a[jj] = fmaf(gv.z, wp2[jj], a[jj]);
                a[jj] = fmaf(gv.w, wp3[jj], a[jj]);
            }
        }
        #pragma unroll
        for (int jj = 0; jj < 16; ++jj) {
            float x = a[jj] * rsI;
            float s1 = x, s2 = x * x;
            #pragma unroll
            for (int m = 32; m; m >>= 1) { s1 += __shfl_xor(s1, m); s2 += __shfl_xor(s2, m); }
            float mu  = s1 * (1.f / NP_N);
            float var = s2 * (1.f / NP_N) - mu * mu;
            float rinv = rsqrtf(var + EPSV);
            float gg = g1[j0 + jj], bb = b1[j0 + jj];
            float y = gg * (x - mu) * rinv + bb;
            float h = (y >= 0.f) ? y : 0.01f * y;
            h = (n < NP_N) ? h : 0.f;
            float s3 = h;
            #pragma unroll
            for (int m = 32; m; m >>= 1) s3 += __shfl_xor(s3, m);
            if (lane == jj) s_r[64 + j0 + jj] = s3 * (1.f / NP_N);
            const float* w2p = W2 + (j0 + jj) * C2_C;
            #pragma unroll
            for (int k = 0; k < C2_C; ++k) zacc[k] = fmaf(h, w2p[k], zacc[k]);
        }
    }
    __syncthreads();
    // s_feat becomes Z buffer
    for (int i = tid; i < 64 * FPAD; i += 256) s_feat[i] = 0.f;
    __syncthreads();
    {
        const float rsO = s_rs[n];
        #pragma unroll
        for (int k = 0; k < C2_C; ++k) atomicAdd(&s_feat[n * FPAD + k], zacc[k] * rsO);
    }
    __syncthreads();
    for (int i = tid; i < 64 * FPAD; i += 256) s_gc[i] = 0.f;
    __syncthreads();
    // conv2 on Z
    for (int i = tid; i < EP_N * 16; i += 256) {
        int e = i >> 4, c4 = (i & 15) << 2;
        int s = s_src[e], d = s_dst[e];
        float w = s_ew[e];
        float4 v = *(const float4*)&s_feat[s * FPAD + c4];
        atomicAdd(&s_gc[d * FPAD + c4 + 0], v.x * w);
        atomicAdd(&s_gc[d * FPAD + c4 + 1], v.y * w);
        atomicAdd(&s_gc[d * FPAD + c4 + 2], v.z * w);
        atomicAdd(&s_gc[d * FPAD + c4 + 3], v.w * w);
    }
    __syncthreads();
    // X2 stats + graph_norm + lrelu + r2 (per channel)
    if (tid < C2_C) {
        int c = tid;
        float s1 = 0.f, s2 = 0.f;
        for (int nn = 0; nn < NP_N; ++nn) {
            float x = s_gc[nn * FPAD + c] * s_rs[64 + nn];
            s1 += x; s2 += x * x;
        }
        float mu  = s1 * (1.f / NP_N);
        float var = s2 * (1.f / NP_N) - mu * mu;
        float rinv = rsqrtf(var + EPSV);
        float gg = g2[c], bb = b2[c];
        float rr = 0.f;
        for (int nn = 0; nn < NP_N; ++nn) {
            float x = s_gc[nn * FPAD + c] * s_rs[64 + nn];
            float y = gg * (x - mu) * rinv + bb;
            rr += (y >= 0.f) ? y : 0.01f * y;
        }
        s_r[320 + c] = rr * (1.f / NP_N);
    }
    __syncthreads();
    // emb = concat(r0,r1,r2) @ We, InstanceNorm(row) + lrelu
    float acc = 0.f;
    if (tid < RD_C) {
        for (int i = 0; i < 384; ++i) acc = fmaf(s_r[i], We[i * RD_C + tid], acc);
    }
    float s1 = (tid < RD_C) ? acc : 0.f;
    float s2 = s1 * s1;
    #pragma unroll
    for (int m = 32; m; m >>= 1) { s1 += __shfl_xor(s1, m); s2 += __shfl_xor(s2, m); }
    if ((lane == 0) && wave < 2) { s_red[wave * 2] = s1; s_red[wave * 2 + 1] = s2; }
    __syncthreads();
    if (tid < RD_C) {
        float tot = s_red[0] + s_red[2];
        float tq  = s_red[1] + s_red[3];
        float mu  = tot * (1.f / RD_C);
        float var = tq * (1.f / RD_C) - mu * mu;
        float y = (acc - mu) * rsqrtf(var + EPSV);
        embout[(size_t)p * RD_C + tid] = (y >= 0.f) ? y : 0.01f * y;
    }
}

// ---------------------------------------------------------------------------
// Mesh graph kernels
// ---------------------------------------------------------------------------
__global__ __launch_bounds__(256) void deg_kernel(
    const int* __restrict__ msrc, const int* __restrict__ mdst,
    float* __restrict__ degO, float* __restrict__ degI)
{
    int e = blockIdx.x * 256 + threadIdx.x;
    if (e < EM_N) {
        atomicAdd(&degO[msrc[e]], 1.f);
        atomicAdd(&degI[mdst[e]], 1.f);
    }
}

// conv1 scatter: emb row-major [PM][128] -> agg1 transposed [128][PM]
__global__ __launch_bounds__(256) void scatter1_kernel(
    const float* __restrict__ emb, const int* __restrict__ msrc,
    const int* __restrict__ mdst, const float* __restrict__ mew,
    const float* __restrict__ degO, float* __restrict__ agg1T)
{
    int idx = blockIdx.x * 256 + threadIdx.x;   // EM * 128 exact
    int e = idx >> 7, c = idx & 127;
    int s = msrc[e], d = mdst[e];
    float v = emb[(size_t)s * RD_C + c] * rsqrtf(fmaxf(degO[s], 1.f)) * mew[e];
    atomicAdd(&agg1T[(size_t)c * PM + d], v);
}

// conv2 scatter: hT [256][PM] -> agg2T [256][PM]; grid (625, 256)
__global__ __launch_bounds__(256) void scatter2_kernel(
    const float* __restrict__ hT, const int* __restrict__ msrc,
    const int* __restrict__ mdst, const float* __restrict__ mew,
    const float* __restrict__ degO, float* __restrict__ agg2T)
{
    int e = blockIdx.x * 256 + threadIdx.x;     // EM exact
    int c = blockIdx.y;
    int s = msrc[e], d = mdst[e];
    float v = hT[(size_t)c * PM + s] * rsqrtf(fmaxf(degO[s], 1.f)) * mew[e];
    atomicAdd(&agg2T[(size_t)c * PM + d], v);
}

// X_T[j][row] = rsqrt(max(degI,1)) * sum_c A_T[c][row] * W[c][j]; N = 256
__global__ __launch_bounds__(256) void mesh_gemm_kernel(
    const float* __restrict__ AT, const float* __restrict__ W,
    const float* __restrict__ degI, float* __restrict__ XT, int K)
{
    const int tid = threadIdx.x, lane = tid & 63, wave = tid >> 6;
    const int row = blockIdx.x * 64 + lane;
    const bool act = row < PM;
    const int rowc = act ? row : (PM - 1);
    const float rs = rsqrtf(fmaxf(degI[rowc], 1.f));
    const int j0 = __builtin_amdgcn_readfirstlane((blockIdx.y * 4 + wave) * 16);
    float a[16];
    #pragma unroll
    for (int jj = 0; jj < 16; ++jj) a[jj] = 0.f;
    for (int c = 0; c < K; ++c) {
        float g = AT[(size_t)c * PM + rowc];
        g = act ? g : 0.f;
        const float* wp = W + c * 256 + j0;
        #pragma unroll
        for (int jj = 0; jj < 16; ++jj) a[jj] = fmaf(g, wp[jj], a[jj]);
    }
    if (act) {
        #pragma unroll
        for (int jj = 0; jj < 16; ++jj) XT[(size_t)(j0 + jj) * PM + row] = a[jj] * rs;
    }
}

__device__ __forceinline__ float block_sum2(float v1, float v2, float* s_red, float* out2)
{
    #pragma unroll
    for (int m = 32; m; m >>= 1) { v1 += __shfl_xor(v1, m); v2 += __shfl_xor(v2, m); }
    int w = threadIdx.x >> 6;
    if ((threadIdx.x & 63) == 0) { s_red[w * 2] = v1; s_red[w * 2 + 1] = v2; }
    __syncthreads();
    float t1 = s_red[0] + s_red[2] + s_red[4] + s_red[6];
    float t2 = s_red[1] + s_red[3] + s_red[5] + s_red[7];
    __syncthreads();
    *out2 = t2;
    return t1;
}

// per-channel sums over rows; grid (40, 256)
__global__ __launch_bounds__(256) void col_stats_kernel(
    const float* __restrict__ X, float* __restrict__ sums, float* __restrict__ sumsq)
{
    __shared__ float s_red[8];
    int c = blockIdx.y;
    int r = blockIdx.x * 256 + threadIdx.x;
    float v = (r < PM) ? X[(size_t)c * PM + r] : 0.f;
    float sq;
    float s = block_sum2(v, v * v, s_red, &sq);
    if (threadIdx.x == 0) {
        atomicAdd(&sums[c], s);
        atomicAdd(&sumsq[c], sq);
    }
}

// graph_norm + lrelu (+optional in-place store) + readout sum; grid (40, 256)
__global__ __launch_bounds__(256) void norm_kernel(
    float* __restrict__ X, const float* __restrict__ sums,
    const float* __restrict__ sumsq, const float* __restrict__ g,
    const float* __restrict__ b, float* __restrict__ ro, int store)
{
    __shared__ float s_red[8];
    int c = blockIdx.y;
    int r = blockIdx.x * 256 + threadIdx.x;
    float mu  = sums[c] * (1.f / PM);
    float var = sumsq[c] * (1.f / PM) - mu * mu;
    float sc  = g[c] * rsqrtf(var + EPSV);
    float h = 0.f;
    if (r < PM) {
        float x = X[(size_t)c * PM + r];
        float y = sc * (x - mu) + b[c];
        h = (y >= 0.f) ? y : 0.01f * y;
        if (store) X[(size_t)c * PM + r] = h;
    }
    float dummy;
    float s = block_sum2(h, 0.f, s_red, &dummy);
    if (threadIdx.x == 0) atomicAdd(&ro[c], s);
}

__global__ __launch_bounds__(256) void final_kernel(
    const float* __restrict__ ro, const float* __restrict__ Wcls,
    float* __restrict__ out)
{
    __shared__ float s_part[256];
    int tid = threadIdx.x;
    int o = tid & 15, seg = tid >> 4;       // 16 segs x 32 j
    float pacc = 0.f;
    for (int j = seg * 32; j < seg * 32 + 32; ++j)
        pacc = fmaf(ro[j] * (1.f / PM), Wcls[j * OUT_C + o], pacc);
    s_part[tid] = pacc;
    __syncthreads();
    if (tid < OUT_C) {
        float a = 0.f;
        #pragma unroll
        for (int s = 0; s < 16; ++s) a += s_part[s * 16 + tid];
        out[tid] = a;
    }
}

extern "C" void kernel_launch(void* const* d_in, const int* in_sizes, int n_in,
                              void* d_out, int out_size, void* d_ws, size_t ws_size,
                              hipStream_t stream) {
    const float* feats = (const float*)d_in[0];
    const int*   psrc  = (const int*)d_in[1];
    const int*   pdst  = (const int*)d_in[2];
    const float* pew   = (const float*)d_in[3];
    const int*   msrc  = (const int*)d_in[4];
    const int*   mdst  = (const int*)d_in[5];
    const float* mew   = (const float*)d_in[6];
    const float* W1    = (const float*)d_in[7];
    const float* g1    = (const float*)d_in[8];
    const float* b1    = (const float*)d_in[9];
    const float* W2    = (const float*)d_in[10];
    const float* g2    = (const float*)d_in[11];
    const float* b2    = (const float*)d_in[12];
    const float* We    = (const float*)d_in[13];
    const float* Wc1   = (const float*)d_in[14];
    const float* g3    = (const float*)d_in[15];
    const float* b3    = (const float*)d_in[16];
    const float* Wc2   = (const float*)d_in[17];
    const float* g4    = (const float*)d_in[18];
    const float* b4    = (const float*)d_in[19];
    const float* Wcls  = (const float*)d_in[20];
    float* out = (float*)d_out;
    float* ws  = (float*)d_ws;

    float* emb   = ws + OFF_EMB;
    float* degO  = ws + OFF_DEGO;
    float* degI  = ws + OFF_DEGI;
    float* agg1T = ws + OFF_AGG1;
    float* hT    = ws + OFF_H;
    float* agg2T = ws + OFF_AGG2;
    float* x2T   = ws + OFF_X2;
    float* sums1  = ws + OFF_STATS;
    float* sumsq1 = ws + OFF_STATS + 256;
    float* sums2  = ws + OFF_STATS + 512;
    float* sumsq2 = ws + OFF_STATS + 768;
    float* ro     = ws + OFF_STATS + 1024;   // [512]

    // zero scratch used by atomics
    hipMemsetAsync(degO,  0, 2 * PM * sizeof(float), stream);           // degO+degI
    hipMemsetAsync(agg1T, 0, (size_t)RD_C * PM * sizeof(float), stream);
    hipMemsetAsync(agg2T, 0, (size_t)256 * PM * sizeof(float), stream);
    hipMemsetAsync(sums1, 0, 1536 * sizeof(float), stream);             // stats + ro

    patch_kernel<<<PM, 256, 0, stream>>>(feats, psrc, pdst, pew,
                                         W1, g1, b1, W2, g2, b2, We, emb);
    deg_kernel<<<EM_N / 256, 256, 0, stream>>>(msrc, mdst, degO, degI);
    scatter1_kernel<<<(EM_N * 128) / 256, 256, 0, stream>>>(emb, msrc, mdst, mew, degO, agg1T);
    mesh_gemm_kernel<<<dim3(157, 4), 256, 0, stream>>>(agg1T, Wc1, degI, hT, RD_C);
    col_stats_kernel<<<dim3(40, 256), 256, 0, stream>>>(hT, sums1, sumsq1);
    norm_kernel<<<dim3(40, 256), 256, 0, stream>>>(hT, sums1, sumsq1, g3, b3, ro, 1);
    scatter2_kernel<<<dim3(EM_N / 256, 256), 256, 0, stream>>>(hT, msrc, mdst, mew, degO, agg2T);
    mesh_gemm_kernel<<<dim3(157, 4), 256, 0, stream>>>(agg2T, Wc2, degI, x2T, 256);
    col_stats_kernel<<<dim3(40, 256), 256, 0, stream>>>(x2T, sums2, sumsq2);
    norm_kernel<<<dim3(40, 256), 256, 0, stream>>>(x2T, sums2, sumsq2, g4, b4, ro + 256, 0);
    final_kernel<<<1, 256, 0, stream>>>(ro, Wcls, out);
}

// Round 2
// 2181.731 us; speedup vs baseline: 3.1057x; 3.1057x over previous
//
#include <hip/hip_runtime.h>
#include <hip/hip_bf16.h>

// Problem constants
#define PM    10000
#define NP_N  50
#define EP_N  200
#define EM_N  160000
#define OUT_C 16
#define EPSV  1e-5f

typedef __attribute__((ext_vector_type(8))) short short8;
typedef __attribute__((ext_vector_type(4))) float f32x4;

// workspace layout (float offsets)
#define OFF_DEGO   0
#define OFF_DEGI   10016
#define OFF_OFFS   20032      // int [10001]
#define OFF_CNT    30048      // int
#define OFF_CUR    40064      // int
#define OFF_CSRC   50080      // int [160000]
#define OFF_CSRW   210080     // f32 [160000]
#define OFF_STATS  370080     // sums1[256] sq1[256] sums2[256] sq2[256] ro[512]
#define OFF_W1S    371616     // 16384 bf16 (8192 f-slots)
#define OFF_W2S    379808     // 16384 bf16
#define OFF_EMB    388000     // f32 [PM][128]
#define OFF_AGG1   1668000    // f32 [128][PM]
#define OFF_X1     2948000    // f32 [256][PM]
#define OFF_HROW   5508000    // bf16 [PM][256] (1280000 f-slots)
#define OFF_AGG2   1668000    // f32 [256][PM]  (overlays AGG1+X1, both dead)
#define OFF_X2     4228000    // f32 [256][PM]  (overlays X1 tail + HROW, both dead)

__device__ __forceinline__ ushort f2bf(float f){
    __hip_bfloat16 h = __float2bfloat16(f);
    return *reinterpret_cast<ushort*>(&h);
}

// ---------------------------------------------------------------------------
// prep: swizzle W1 [64][256] and W2 [256][64] into bf16 MFMA B-fragment order
// ---------------------------------------------------------------------------
__global__ __launch_bounds__(256) void prep_kernel(
    const float* __restrict__ W1, const float* __restrict__ W2,
    ushort* __restrict__ W1s, ushort* __restrict__ W2s)
{
    int gid = blockIdx.x * 256 + threadIdx.x;
    if (gid < 16384){
        int j = gid & 7, l = (gid >> 3) & 63, ki = (gid >> 9) & 1, ct = gid >> 10;
        int k = ki * 32 + ((l >> 4) << 3) + j;
        int n = ct * 16 + (l & 15);
        W1s[gid] = f2bf(W1[k * 256 + n]);
    } else {
        int g = gid - 16384;
        int j = g & 7, l = (g >> 3) & 63, ki = (g >> 9) & 7, ct = g >> 12;
        int k = ki * 32 + ((l >> 4) << 3) + j;
        int n = ct * 16 + (l & 15);
        W2s[g] = f2bf(W2[k * 64 + n]);
    }
}

// ---------------------------------------------------------------------------
// Patch embedder (MFMA). One block (4 waves) per patch.
// ---------------------------------------------------------------------------
__global__ __launch_bounds__(256, 4) void patch_kernel(
    const float* __restrict__ feats, const int* __restrict__ esrc,
    const int* __restrict__ edst, const float* __restrict__ eew,
    const ushort* __restrict__ W1s, const float* __restrict__ g1,
    const float* __restrict__ b1, const ushort* __restrict__ W2s,
    const float* __restrict__ g2, const float* __restrict__ b2,
    const float* __restrict__ We, float* __restrict__ embout)
{
    __shared__ __align__(16) char smem[39808];
    float* s_feat = (float*)smem;               // [64][68] f32 (feat -> Z)
    float* s_gc   = (float*)(smem + 17408);     // [64][68] f32 (gc1 -> gc2)
    char*  s_h1   = smem;                        // bf16 [64][264], XOR-swizzled
    int*   s_src  = (int*)(smem + 34816);
    int*   s_dst  = (int*)(smem + 35616);
    float* s_ew   = (float*)(smem + 36416);     // edges end @37216
    float* s_part = (float*)(smem + 34816);     // 512 f, overlays edges post-conv2
    float* s_deg  = (float*)(smem + 37216);     // 128
    float* s_scale= (float*)(smem + 37216);     // overlay deg (dead)
    float* s_shift= (float*)(smem + 37216 + 256);
    float* s_rs   = (float*)(smem + 37728);     // 128
    float* s_r    = (float*)(smem + 38240);     // 384
    float* s_red  = (float*)(smem + 39776);     // 8

    const int tid  = threadIdx.x;
    const int p    = blockIdx.x;
    const int lane = tid & 63;
    const int wv   = tid >> 6;

    for (int i = tid; i < 4352; i += 256) s_gc[i] = 0.f;
    for (int i = tid; i < 384; i += 256) s_r[i] = 0.f;
    if (tid < 128) s_deg[tid] = 0.f;
    if (tid < EP_N){
        s_src[tid] = esrc[p * EP_N + tid];
        s_dst[tid] = edst[p * EP_N + tid];
        s_ew[tid]  = eew[p * EP_N + tid];
    }
    __syncthreads();
    if (tid < EP_N){
        atomicAdd(&s_deg[s_src[tid]], 1.f);
        atomicAdd(&s_deg[64 + s_dst[tid]], 1.f);
    }
    for (int i = tid; i < 800; i += 256){
        int n = i >> 4, c4 = (i & 15) << 2;
        *(float4*)&s_feat[n * 68 + c4] =
            *(const float4*)&feats[(size_t)p * 3200 + n * 64 + c4];
    }
    __syncthreads();
    if (tid < 128) s_rs[tid] = rsqrtf(fmaxf(s_deg[tid], 1.f));
    __syncthreads();
    // r0 partial + fold rsqrt(deg_out) into feat (single owner per element)
    {
        int c = tid & 63, q = tid >> 6;
        int n0 = q * 13, n1 = min(50, n0 + 13);
        float part = 0.f;
        for (int n = n0; n < n1; ++n){
            float v = s_feat[n * 68 + c];
            part += v;
            s_feat[n * 68 + c] = v * s_rs[n];
        }
        atomicAdd(&s_r[c], part * 0.02f);
    }
    __syncthreads();
    // conv1: edge scatter
    for (int i = tid; i < 3200; i += 256){
        int e = i >> 4, c4 = (i & 15) << 2;
        int s = s_src[e], d = s_dst[e];
        float wgt = s_ew[e];
        float4 v = *(const float4*)&s_feat[s * 68 + c4];
        atomicAdd(&s_gc[d * 68 + c4 + 0], v.x * wgt);
        atomicAdd(&s_gc[d * 68 + c4 + 1], v.y * wgt);
        atomicAdd(&s_gc[d * 68 + c4 + 2], v.z * wgt);
        atomicAdd(&s_gc[d * 68 + c4 + 3], v.w * wgt);
    }
    __syncthreads();
    // fold rsqrt(deg_in)
    for (int i = tid; i < 800; i += 256){
        int n = i >> 4, c4 = (i & 15) << 2;
        float sc = s_rs[64 + n];
        float4 v = *(float4*)&s_gc[n * 68 + c4];
        v.x *= sc; v.y *= sc; v.z *= sc; v.w *= sc;
        *(float4*)&s_gc[n * 68 + c4] = v;
    }
    __syncthreads();

    // ---- GEMM1 (MFMA): X1 = gc @ W1, fused graph_norm + lrelu + r1 + h1 store
    short8 af[4][2];
    {
        int arow = lane & 15, ag = lane >> 4;
        #pragma unroll
        for (int rt = 0; rt < 4; ++rt)
            #pragma unroll
            for (int ki = 0; ki < 2; ++ki){
                int row = rt * 16 + arow;
                int k0 = ki * 32 + ag * 8;
                float4 f0 = *(const float4*)&s_gc[row * 68 + k0];
                float4 f1 = *(const float4*)&s_gc[row * 68 + k0 + 4];
                short8 s;
                s[0]=(short)f2bf(f0.x); s[1]=(short)f2bf(f0.y);
                s[2]=(short)f2bf(f0.z); s[3]=(short)f2bf(f0.w);
                s[4]=(short)f2bf(f1.x); s[5]=(short)f2bf(f1.y);
                s[6]=(short)f2bf(f1.z); s[7]=(short)f2bf(f1.w);
                af[rt][ki] = s;
            }
    }
    __syncthreads();   // all gc reads complete; h1 may now overwrite buf

    #pragma unroll
    for (int ct4 = 0; ct4 < 4; ++ct4){
        int ctg = wv * 4 + ct4;
        int j = ctg * 16 + (lane & 15);
        short8 wb0 = *(const short8*)&W1s[((ctg * 2 + 0) * 64 + lane) * 8];
        short8 wb1 = *(const short8*)&W1s[((ctg * 2 + 1) * 64 + lane) * 8];
        f32x4 acc[4];
        #pragma unroll
        for (int rt = 0; rt < 4; ++rt) acc[rt] = (f32x4){0.f,0.f,0.f,0.f};
        #pragma unroll
        for (int rt = 0; rt < 4; ++rt){
            acc[rt] = __builtin_amdgcn_mfma_f32_16x16x32_bf16(af[rt][0], wb0, acc[rt], 0,0,0);
            acc[rt] = __builtin_amdgcn_mfma_f32_16x16x32_bf16(af[rt][1], wb1, acc[rt], 0,0,0);
        }
        float s1 = 0.f, s2 = 0.f;
        #pragma unroll
        for (int rt = 0; rt < 4; ++rt)
            #pragma unroll
            for (int e = 0; e < 4; ++e){ float x = acc[rt][e]; s1 += x; s2 += x*x; }
        s1 += __shfl_xor(s1, 16); s1 += __shfl_xor(s1, 32);
        s2 += __shfl_xor(s2, 16); s2 += __shfl_xor(s2, 32);
        float mu = s1 * 0.02f;
        float var = s2 * 0.02f - mu * mu;
        float rinv = rsqrtf(var + EPSV);
        float sc = g1[j] * rinv;
        float sh = b1[j] - mu * sc;
        float r1p = 0.f;
        int rbase = (lane >> 4) * 4;
        #pragma unroll
        for (int rt = 0; rt < 4; ++rt)
            #pragma unroll
            for (int e = 0; e < 4; ++e){
                int row = rt * 16 + rbase + e;
                float y = acc[rt][e] * sc + sh;
                float h = (y >= 0.f) ? y : 0.01f * y;
                h = (row < 50) ? h : 0.f;
                r1p += h;
                int byte = row * 528 + ((j * 2) ^ ((row & 7) << 4));
                *(ushort*)(s_h1 + byte) = f2bf(h);
            }
        r1p += __shfl_xor(r1p, 16); r1p += __shfl_xor(r1p, 32);
        if ((lane >> 4) == 0) s_r[64 + j] = r1p * 0.02f;
    }
    __syncthreads();

    // ---- GEMM2 (MFMA): Z = h1 @ W2
    f32x4 zacc[4];
    #pragma unroll
    for (int rt = 0; rt < 4; ++rt) zacc[rt] = (f32x4){0.f,0.f,0.f,0.f};
    {
        int arow = lane & 15, ag = lane >> 4;
        #pragma unroll
        for (int ki = 0; ki < 8; ++ki){
            short8 wb = *(const short8*)&W2s[((wv * 8 + ki) * 64 + lane) * 8];
            int k0 = ki * 32 + ag * 8;
            #pragma unroll
            for (int rt = 0; rt < 4; ++rt){
                int row = rt * 16 + arow;
                int byte = row * 528 + ((k0 * 2) ^ ((row & 7) << 4));
                short8 a = *(const short8*)(s_h1 + byte);
                zacc[rt] = __builtin_amdgcn_mfma_f32_16x16x32_bf16(a, wb, zacc[rt], 0,0,0);
            }
        }
    }
    __syncthreads();   // h1 dead
    // Z*rsO -> s_feat; zero s_gc
    for (int i = tid; i < 4352; i += 256) s_gc[i] = 0.f;
    {
        int col = wv * 16 + (lane & 15);
        int rbase = (lane >> 4) * 4;
        #pragma unroll
        for (int rt = 0; rt < 4; ++rt)
            #pragma unroll
            for (int e = 0; e < 4; ++e){
                int row = rt * 16 + rbase + e;
                s_feat[row * 68 + col] = zacc[rt][e] * s_rs[row];
            }
    }
    __syncthreads();
    // conv2
    for (int i = tid; i < 3200; i += 256){
        int e = i >> 4, c4 = (i & 15) << 2;
        int s = s_src[e], d = s_dst[e];
        float wgt = s_ew[e];
        float4 v = *(const float4*)&s_feat[s * 68 + c4];
        atomicAdd(&s_gc[d * 68 + c4 + 0], v.x * wgt);
        atomicAdd(&s_gc[d * 68 + c4 + 1], v.y * wgt);
        atomicAdd(&s_gc[d * 68 + c4 + 2], v.z * wgt);
        atomicAdd(&s_gc[d * 68 + c4 + 3], v.w * wgt);
    }
    __syncthreads();
    // X2 stats (parallel over 256 threads)
    {
        int c = tid & 63, q = tid >> 6;
        int n0 = q * 13, n1 = min(50, n0 + 13);
        float s1 = 0.f, s2 = 0.f;
        for (int n = n0; n < n1; ++n){
            float x = s_gc[n * 68 + c] * s_rs[64 + n];
            s1 += x; s2 += x * x;
        }
        s_part[tid] = s1; s_part[256 + tid] = s2;
    }
    __syncthreads();
    if (tid < 64){
        float S1 = 0.f, S2 = 0.f;
        #pragma unroll
        for (int q = 0; q < 4; ++q){ S1 += s_part[q*64 + tid]; S2 += s_part[256 + q*64 + tid]; }
        float mu = S1 * 0.02f, var = S2 * 0.02f - mu * mu;
        float rinv = rsqrtf(var + EPSV);
        float sc = g2[tid] * rinv;
        s_scale[tid] = sc;
        s_shift[tid] = b2[tid] - mu * sc;
    }
    __syncthreads();
    {
        int c = tid & 63, q = tid >> 6;
        int n0 = q * 13, n1 = min(50, n0 + 13);
        float sc = s_scale[c], sh = s_shift[c];
        float rp = 0.f;
        for (int n = n0; n < n1; ++n){
            float x = s_gc[n * 68 + c] * s_rs[64 + n];
            float y = sc * x + sh;
            rp += (y >= 0.f) ? y : 0.01f * y;
        }
        atomicAdd(&s_r[320 + c], rp * 0.02f);
    }
    __syncthreads();
    // emb = r @ We, InstanceNorm + lrelu
    {
        int o = tid & 127, half = tid >> 7;
        float acc = 0.f;
        for (int i = half * 192; i < half * 192 + 192; ++i)
            acc = fmaf(s_r[i], We[i * 128 + o], acc);
        s_part[tid] = acc;
    }
    __syncthreads();
    float v = 0.f;
    if (tid < 128) v = s_part[tid] + s_part[tid + 128];
    float s1 = (tid < 128) ? v : 0.f;
    float s2 = s1 * s1;
    #pragma unroll
    for (int m = 32; m; m >>= 1){ s1 += __shfl_xor(s1, m); s2 += __shfl_xor(s2, m); }
    if (lane == 0 && wv < 2){ s_red[wv*2] = s1; s_red[wv*2+1] = s2; }
    __syncthreads();
    if (tid < 128){
        float T1 = s_red[0] + s_red[2], T2 = s_red[1] + s_red[3];
        float mu = T1 * (1.f/128.f), var = T2 * (1.f/128.f) - mu * mu;
        float y = (v - mu) * rsqrtf(var + EPSV);
        embout[(size_t)p * 128 + tid] = (y >= 0.f) ? y : 0.01f * y;
    }
}

// ---------------------------------------------------------------------------
// Mesh: degrees + CSR build
// ---------------------------------------------------------------------------
__global__ __launch_bounds__(256) void deg_kernel(
    const int* __restrict__ msrc, const int* __restrict__ mdst,
    float* __restrict__ degO, float* __restrict__ degI, int* __restrict__ cnt)
{
    int e = blockIdx.x * 256 + threadIdx.x;
    if (e < EM_N){
        int s = msrc[e], d = mdst[e];
        atomicAdd(&degO[s], 1.f);
        atomicAdd(&degI[d], 1.f);
        atomicAdd(&cnt[d], 1);
    }
}

__global__ __launch_bounds__(256) void scan_kernel(
    const int* __restrict__ cnt, int* __restrict__ offs)
{
    __shared__ int s_sc[256];
    int t = threadIdx.x;
    int sum = 0;
    for (int k = 0; k < 40; ++k){ int i = t*40 + k; if (i < PM) sum += cnt[i]; }
    s_sc[t] = sum;
    __syncthreads();
    for (int off = 1; off < 256; off <<= 1){
        int v = (t >= off) ? s_sc[t - off] : 0;
        __syncthreads();
        s_sc[t] += v;
        __syncthreads();
    }
    int run = s_sc[t] - sum;   // exclusive
    for (int k = 0; k < 40; ++k){
        int i = t*40 + k;
        if (i < PM){ offs[i] = run; run += cnt[i]; }
    }
    if (t == 255) offs[PM] = s_sc[255];
}

__global__ __launch_bounds__(256) void fill_kernel(
    const int* __restrict__ msrc, const int* __restrict__ mdst,
    const float* __restrict__ mew, const float* __restrict__ degO,
    const int* __restrict__ offs, int* __restrict__ cur,
    int* __restrict__ csrc, float* __restrict__ csw)
{
    int e = blockIdx.x * 256 + threadIdx.x;
    if (e < EM_N){
        int d = mdst[e], s = msrc[e];
        int pos = atomicAdd(&cur[d], 1);
        int idx = offs[d] + pos;
        csrc[idx] = s;
        csw[idx] = mew[e] * rsqrtf(fmaxf(degO[s], 1.f));
    }
}

// gather conv1: emb [PM][128] f32 -> agg1T [128][PM], rsI folded
__global__ __launch_bounds__(256) void gather1_kernel(
    const float* __restrict__ emb, const int* __restrict__ offs,
    const int* __restrict__ csrc, const float* __restrict__ csw,
    const float* __restrict__ degI, float* __restrict__ aggT)
{
    int lane = threadIdx.x & 63, w = threadIdx.x >> 6;
    int d = blockIdx.x * 64 + lane;
    float acc[32];
    #pragma unroll
    for (int j = 0; j < 32; ++j) acc[j] = 0.f;
    if (d < PM){
        int e0 = offs[d], e1 = offs[d+1];
        for (int i = e0; i < e1; ++i){
            int s = csrc[i]; float wt = csw[i];
            const float* src = emb + (size_t)s * 128 + w * 32;
            #pragma unroll
            for (int j4 = 0; j4 < 8; ++j4){
                float4 vv = *(const float4*)(src + j4*4);
                acc[j4*4+0] = fmaf(vv.x, wt, acc[j4*4+0]);
                acc[j4*4+1] = fmaf(vv.y, wt, acc[j4*4+1]);
                acc[j4*4+2] = fmaf(vv.z, wt, acc[j4*4+2]);
                acc[j4*4+3] = fmaf(vv.w, wt, acc[j4*4+3]);
            }
        }
        float rs = rsqrtf(fmaxf(degI[d], 1.f));
        #pragma unroll
        for (int j = 0; j < 32; ++j) aggT[(size_t)(w*32 + j) * PM + d] = acc[j] * rs;
    }
}

// gather conv2: hRow [PM][256] bf16 -> agg2T [256][PM], rsI folded
__global__ __launch_bounds__(256) void gather2_kernel(
    const ushort* __restrict__ hRow, const int* __restrict__ offs,
    const int* __restrict__ csrc, const float* __restrict__ csw,
    const float* __restrict__ degI, float* __restrict__ aggT)
{
    int lane = threadIdx.x & 63, w = threadIdx.x >> 6;
    int d = blockIdx.x * 64 + lane;
    float acc[64];
    #pragma unroll
    for (int j = 0; j < 64; ++j) acc[j] = 0.f;
    if (d < PM){
        int e0 = offs[d], e1 = offs[d+1];
        for (int i = e0; i < e1; ++i){
            int s = csrc[i]; float wt = csw[i];
            const ushort* src = hRow + (size_t)s * 256 + w * 64;
            #pragma unroll
            for (int q4 = 0; q4 < 8; ++q4){
                uint4 qv = *(const uint4*)(src + q4*8);
                unsigned u;
                u = qv.x;
                acc[q4*8+0] = fmaf(__uint_as_float(u << 16), wt, acc[q4*8+0]);
                acc[q4*8+1] = fmaf(__uint_as_float(u & 0xffff0000u), wt, acc[q4*8+1]);
                u = qv.y;
                acc[q4*8+2] = fmaf(__uint_as_float(u << 16), wt, acc[q4*8+2]);
                acc[q4*8+3] = fmaf(__uint_as_float(u & 0xffff0000u), wt, acc[q4*8+3]);
                u = qv.z;
                acc[q4*8+4] = fmaf(__uint_as_float(u << 16), wt, acc[q4*8+4]);
                acc[q4*8+5] = fmaf(__uint_as_float(u & 0xffff0000u), wt, acc[q4*8+5]);
                u = qv.w;
                acc[q4*8+6] = fmaf(__uint_as_float(u << 16), wt, acc[q4*8+6]);
                acc[q4*8+7] = fmaf(__uint_as_float(u & 0xffff0000u), wt, acc[q4*8+7]);
            }
        }
        float rs = rsqrtf(fmaxf(degI[d], 1.f));
        #pragma unroll
        for (int j = 0; j < 64; ++j) aggT[(size_t)(w*64 + j) * PM + d] = acc[j] * rs;
    }
}

// XT[j][row] = sum_c AT[c][row] * W[c][j];  N=256 out cols
__global__ __launch_bounds__(256) void mesh_gemm_kernel(
    const float* __restrict__ AT, const float* __restrict__ W,
    float* __restrict__ XT, int K)
{
    const int tid = threadIdx.x, lane = tid & 63, wave = tid >> 6;
    const int row = blockIdx.x * 64 + lane;
    const bool act = row < PM;
    const int rowc = act ? row : (PM - 1);
    const int j0 = __builtin_amdgcn_readfirstlane((blockIdx.y * 4 + wave) * 16);
    float a[16];
    #pragma unroll
    for (int jj = 0; jj < 16; ++jj) a[jj] = 0.f;
    for (int c = 0; c < K; ++c){
        float g = AT[(size_t)c * PM + rowc];
        g = act ? g : 0.f;
        const float* wp = W + c * 256 + j0;
        #pragma unroll
        for (int jj = 0; jj < 16; ++jj) a[jj] = fmaf(g, wp[jj], a[jj]);
    }
    if (act){
        #pragma unroll
        for (int jj = 0; jj < 16; ++jj) XT[(size_t)(j0 + jj) * PM + row] = a[jj];
    }
}

__device__ __forceinline__ float block_sum2(float v1, float v2, float* s_red, float* out2)
{
    #pragma unroll
    for (int m = 32; m; m >>= 1){ v1 += __shfl_xor(v1, m); v2 += __shfl_xor(v2, m); }
    int w = threadIdx.x >> 6;
    if ((threadIdx.x & 63) == 0){ s_red[w*2] = v1; s_red[w*2+1] = v2; }
    __syncthreads();
    float t1 = s_red[0] + s_red[2] + s_red[4] + s_red[6];
    float t2 = s_red[1] + s_red[3] + s_red[5] + s_red[7];
    __syncthreads();
    *out2 = t2;
    return t1;
}

__global__ __launch_bounds__(256) void col_stats_kernel(
    const float* __restrict__ X, float* __restrict__ sums, float* __restrict__ sumsq)
{
    __shared__ float s_red[8];
    int c = blockIdx.y;
    int r = blockIdx.x * 256 + threadIdx.x;
    float v = (r < PM) ? X[(size_t)c * PM + r] : 0.f;
    float sq;
    float s = block_sum2(v, v * v, s_red, &sq);
    if (threadIdx.x == 0){ atomicAdd(&sums[c], s); atomicAdd(&sumsq[c], sq); }
}

// layer-1 norm + lrelu + transpose to row-major bf16 + readout
__global__ __launch_bounds__(256) void norm1t_kernel(
    const float* __restrict__ x1T, const float* __restrict__ sums,
    const float* __restrict__ sumsq, const float* __restrict__ g,
    const float* __restrict__ b, float* __restrict__ ro, ushort* __restrict__ hRow)
{
    __shared__ float s_tile[64][65];
    int lane = threadIdx.x & 63, wvv = threadIdx.x >> 6;
    int cg = blockIdx.y;
    int rb = blockIdx.x * 64;
    int r = rb + lane;
    for (int cc = wvv; cc < 64; cc += 4){
        int c = cg * 64 + cc;
        float mu = sums[c] * (1.f / PM);
        float var = sumsq[c] * (1.f / PM) - mu * mu;
        float sc = g[c] * rsqrtf(var + EPSV);
        float sh = b[c] - mu * sc;
        float h = 0.f;
        if (r < PM){
            float x = x1T[(size_t)c * PM + r];
            float y = sc * x + sh;
            h = (y >= 0.f) ? y : 0.01f * y;
        }
        s_tile[cc][lane] = h;
        float t = h;
        #pragma unroll
        for (int m = 32; m; m >>= 1) t += __shfl_xor(t, m);
        if (lane == 0) atomicAdd(&ro[c], t);
    }
    __syncthreads();
    for (int i = wvv; i < 64; i += 4){
        int rr = rb + i;
        if (rr < PM) hRow[(size_t)rr * 256 + cg * 64 + lane] = f2bf(s_tile[i][lane]);
    }
}

// layer-2 norm + lrelu + readout (no store)
__global__ __launch_bounds__(256) void norm2_kernel(
    const float* __restrict__ X, const float* __restrict__ sums,
    const float* __restrict__ sumsq, const float* __restrict__ g,
    const float* __restrict__ b, float* __restrict__ ro)
{
    __shared__ float s_red[8];
    int c = blockIdx.y;
    int r = blockIdx.x * 256 + threadIdx.x;
    float mu = sums[c] * (1.f / PM);
    float var = sumsq[c] * (1.f / PM) - mu * mu;
    float sc = g[c] * rsqrtf(var + EPSV);
    float h = 0.f;
    if (r < PM){
        float x = X[(size_t)c * PM + r];
        float y = sc * (x - mu) + b[c];
        h = (y >= 0.f) ? y : 0.01f * y;
    }
    float dummy;
    float s = block_sum2(h, 0.f, s_red, &dummy);
    if (threadIdx.x == 0) atomicAdd(&ro[c], s);
}

__global__ __launch_bounds__(256) void final_kernel(
    const float* __restrict__ ro, const float* __restrict__ Wcls,
    float* __restrict__ out)
{
    __shared__ float s_part[256];
    int tid = threadIdx.x;
    int o = tid & 15, seg = tid >> 4;
    float pacc = 0.f;
    for (int j = seg * 32; j < seg * 32 + 32; ++j)
        pacc = fmaf(ro[j] * (1.f / PM), Wcls[j * OUT_C + o], pacc);
    s_part[tid] = pacc;
    __syncthreads();
    if (tid < OUT_C){
        float a = 0.f;
        #pragma unroll
        for (int s = 0; s < 16; ++s) a += s_part[s * 16 + tid];
        out[tid] = a;
    }
}

extern "C" void kernel_launch(void* const* d_in, const int* in_sizes, int n_in,
                              void* d_out, int out_size, void* d_ws, size_t ws_size,
                              hipStream_t stream) {
    const float* feats = (const float*)d_in[0];
    const int*   psrc  = (const int*)d_in[1];
    const int*   pdst  = (const int*)d_in[2];
    const float* pew   = (const float*)d_in[3];
    const int*   msrc  = (const int*)d_in[4];
    const int*   mdst  = (const int*)d_in[5];
    const float* mew   = (const float*)d_in[6];
    const float* W1    = (const float*)d_in[7];
    const float* g1    = (const float*)d_in[8];
    const float* b1    = (const float*)d_in[9];
    const float* W2    = (const float*)d_in[10];
    const float* g2    = (const float*)d_in[11];
    const float* b2    = (const float*)d_in[12];
    const float* We    = (const float*)d_in[13];
    const float* Wc1   = (const float*)d_in[14];
    const float* g3    = (const float*)d_in[15];
    const float* b3    = (const float*)d_in[16];
    const float* Wc2   = (const float*)d_in[17];
    const float* g4    = (const float*)d_in[18];
    const float* b4    = (const float*)d_in[19];
    const float* Wcls  = (const float*)d_in[20];
    float* out = (float*)d_out;
    float* ws  = (float*)d_ws;

    float*  degO  = ws + OFF_DEGO;
    float*  degI  = ws + OFF_DEGI;
    int*    offs  = (int*)(ws + OFF_OFFS);
    int*    cnt   = (int*)(ws + OFF_CNT);
    int*    cur   = (int*)(ws + OFF_CUR);
    int*    csrc  = (int*)(ws + OFF_CSRC);
    float*  csw   = ws + OFF_CSRW;
    float*  sums1 = ws + OFF_STATS;
    float*  sumsq1= ws + OFF_STATS + 256;
    float*  sums2 = ws + OFF_STATS + 512;
    float*  sumsq2= ws + OFF_STATS + 768;
    float*  ro    = ws + OFF_STATS + 1024;   // [512]
    ushort* W1s   = (ushort*)(ws + OFF_W1S);
    ushort* W2s   = (ushort*)(ws + OFF_W2S);
    float*  emb   = ws + OFF_EMB;
    float*  agg1T = ws + OFF_AGG1;
    float*  x1T   = ws + OFF_X1;
    ushort* hRow  = (ushort*)(ws + OFF_HROW);
    float*  agg2T = ws + OFF_AGG2;
    float*  x2T   = ws + OFF_X2;

    hipMemsetAsync(degO, 0, 20032 * sizeof(float), stream);   // degO+degI
    hipMemsetAsync(cnt,  0, 10016 * sizeof(int), stream);
    hipMemsetAsync(cur,  0, 10016 * sizeof(int), stream);
    hipMemsetAsync(sums1,0, 1536 * sizeof(float), stream);

    prep_kernel<<<128, 256, 0, stream>>>(W1, W2, W1s, W2s);
    patch_kernel<<<PM, 256, 0, stream>>>(feats, psrc, pdst, pew,
                                         W1s, g1, b1, W2s, g2, b2, We, emb);
    deg_kernel<<<EM_N/256, 256, 0, stream>>>(msrc, mdst, degO, degI, cnt);
    scan_kernel<<<1, 256, 0, stream>>>(cnt, offs);
    fill_kernel<<<EM_N/256, 256, 0, stream>>>(msrc, mdst, mew, degO, offs, cur, csrc, csw);
    gather1_kernel<<<157, 256, 0, stream>>>(emb, offs, csrc, csw, degI, agg1T);
    mesh_gemm_kernel<<<dim3(157, 4), 256, 0, stream>>>(agg1T, Wc1, x1T, 128);
    col_stats_kernel<<<dim3(40, 256), 256, 0, stream>>>(x1T, sums1, sumsq1);
    norm1t_kernel<<<dim3(157, 4), 256, 0, stream>>>(x1T, sums1, sumsq1, g3, b3, ro, hRow);
    gather2_kernel<<<157, 256, 0, stream>>>(hRow, offs, csrc, csw, degI, agg2T);
    mesh_gemm_kernel<<<dim3(157, 4), 256, 0, stream>>>(agg2T, Wc2, x2T, 256);
    col_stats_kernel<<<dim3(40, 256), 256, 0, stream>>>(x2T, sums2, sumsq2);
    norm2_kernel<<<dim3(40, 256), 256, 0, stream>>>(x2T, sums2, sumsq2, g4, b4, ro + 256);
    final_kernel<<<1, 256, 0, stream>>>(ro, Wcls, out);
}

// Round 3
// 926.615 us; speedup vs baseline: 7.3125x; 2.3545x over previous
//
#include <hip/hip_runtime.h>
#include <hip/hip_bf16.h>

// Problem constants
#define PM    10000
#define NP_N  50
#define EP_N  200
#define EM_N  160000
#define OUT_C 16
#define EPSV  1e-5f

typedef __attribute__((ext_vector_type(8))) short short8;
typedef __attribute__((ext_vector_type(4))) float f32x4;

// workspace layout (float offsets)
#define OFF_DEGO   0
#define OFF_DEGI   10016
#define OFF_OFFS   20032      // int [10001]
#define OFF_CNT    30048      // int
#define OFF_CUR    40064      // int
#define OFF_CSRC   50080      // int [160000]
#define OFF_CSRW   210080     // f32 [160000]
#define OFF_STATS  370080     // sums1[256] sq1[256] sums2[256] sq2[256] ro[512]
#define OFF_W1S    371616     // 16384 bf16 (8192 f-slots)
#define OFF_W2S    379808     // 16384 bf16
#define OFF_EMB    388000     // f32 [PM][128]
#define OFF_AGG1   1668000    // f32 [128][PM]
#define OFF_X1     2948000    // f32 [256][PM]
#define OFF_HROW   5508000    // bf16 [PM][256] (1280000 f-slots)
#define OFF_AGG2   1668000    // f32 [256][PM]  (overlays AGG1+X1, both dead)
#define OFF_X2     4228000    // f32 [256][PM]  (overlays X1 tail + HROW, both dead)

__device__ __forceinline__ ushort f2bf(float f){
    __hip_bfloat16 h = __float2bfloat16(f);
    return *reinterpret_cast<ushort*>(&h);
}

// ---------------------------------------------------------------------------
// prep: swizzle W1 [64][256] and W2 [256][64] into bf16 MFMA B-fragment order
// B-frag convention (HW-verified round 2): element B[k][n] with
// k = ki*32 + (l>>4)*8 + j, n = ct*16 + (l&15) lives at frag[((ct*2+ki)*64+l)*8+j]
// ---------------------------------------------------------------------------
__global__ __launch_bounds__(256) void prep_kernel(
    const float* __restrict__ W1, const float* __restrict__ W2,
    ushort* __restrict__ W1s, ushort* __restrict__ W2s)
{
    int gid = blockIdx.x * 256 + threadIdx.x;
    if (gid < 16384){
        int j = gid & 7, l = (gid >> 3) & 63, ki = (gid >> 9) & 1, ct = gid >> 10;
        int k = ki * 32 + ((l >> 4) << 3) + j;
        int n = ct * 16 + (l & 15);
        W1s[gid] = f2bf(W1[k * 256 + n]);
    } else {
        int g = gid - 16384;
        int j = g & 7, l = (g >> 3) & 63, ki = (g >> 9) & 7, ct = g >> 12;
        int k = ki * 32 + ((l >> 4) << 3) + j;
        int n = ct * 16 + (l & 15);
        W2s[g] = f2bf(W2[k * 64 + n]);
    }
}

// ---------------------------------------------------------------------------
// Patch embedder: all-MFMA. One block (4 waves) per patch.
// Convs are MFMA against the normalized adjacency Ã (200 LDS atomics to build).
// ---------------------------------------------------------------------------
__global__ __launch_bounds__(256, 4) void patch_kernel(
    const float* __restrict__ feats, const int* __restrict__ esrc,
    const int* __restrict__ edst, const float* __restrict__ eew,
    const ushort* __restrict__ W1s, const float* __restrict__ g1,
    const float* __restrict__ b1, const ushort* __restrict__ W2s,
    const float* __restrict__ g2, const float* __restrict__ b2,
    const float* __restrict__ We, float* __restrict__ embout)
{
    __shared__ __align__(16) char smem[38432];
    float*  s_A   = (float*)smem;            // [64][68] f32 (dies after frag extract)
    char*   s_h1  = smem;                    // bf16 half-h1 [64 rows][272B], swizzled
    ushort* s_fB  = (ushort*)(smem + 17408); // feat B-frags, 4096 u16
    ushort* s_ZB  = (ushort*)(smem + 17408); // Z B-frags (overlays s_fB)
    char*   s_G1  = smem + 25600;            // G1 bf16 [64][144B], swizzled
    float*  s_part= (float*)(smem + 34816);  // 256 f32
    float*  s_deg = (float*)(smem + 35840);  // 128
    float*  s_rs  = (float*)(smem + 36352);  // 128
    float*  s_r   = (float*)(smem + 36864);  // 384
    float*  s_red = (float*)(smem + 38400);  // 8

    const int tid  = threadIdx.x;
    const int p    = blockIdx.x;
    const int lane = tid & 63;
    const int wv   = tid >> 6;
    const int lnlo = lane & 15;
    const int lghi = lane >> 4;

    // ---- init
    for (int i = tid; i < 4352; i += 256) s_A[i] = 0.f;
    for (int i = tid; i < 2048; i += 256) ((uint*)s_fB)[i] = 0u;   // zero feat frags (rows>=50)
    if (tid < 128) s_deg[tid] = 0.f;
    int es = 0, ed = 0; float ewt = 0.f;
    if (tid < EP_N){
        es  = esrc[p * EP_N + tid];
        ed  = edst[p * EP_N + tid];
        ewt = eew[p * EP_N + tid];
    }
    __syncthreads();
    if (tid < EP_N){
        atomicAdd(&s_deg[es], 1.f);
        atomicAdd(&s_deg[64 + ed], 1.f);
        atomicAdd(&s_A[ed * 68 + es], ewt);
    }
    // ---- feat load -> B-frag LDS (bf16) + r0 partials
    float4 facc = make_float4(0.f, 0.f, 0.f, 0.f);
    for (int i = tid; i < 800; i += 256){
        int s = i >> 4, cq = i & 15;
        float4 v = *(const float4*)&feats[(size_t)p * 3200 + s * 64 + cq * 4];
        facc.x += v.x; facc.y += v.y; facc.z += v.z; facc.w += v.w;
        int ki = s >> 5, ag = (s & 31) >> 3, j = s & 7;
        float vv[4] = {v.x, v.y, v.z, v.w};
        #pragma unroll
        for (int u = 0; u < 4; ++u){
            int c = cq * 4 + u;
            s_fB[(((c >> 4) * 2 + ki) * 64 + ag * 16 + (c & 15)) * 8 + j] = f2bf(vv[u]);
        }
    }
    facc.x += __shfl_xor(facc.x, 16); facc.x += __shfl_xor(facc.x, 32);
    facc.y += __shfl_xor(facc.y, 16); facc.y += __shfl_xor(facc.y, 32);
    facc.z += __shfl_xor(facc.z, 16); facc.z += __shfl_xor(facc.z, 32);
    facc.w += __shfl_xor(facc.w, 16); facc.w += __shfl_xor(facc.w, 32);
    if (lghi == 0) *(float4*)&s_part[(wv * 16 + lnlo) * 4] = facc;
    __syncthreads();
    if (tid < 128) s_rs[tid] = rsqrtf(fmaxf(s_deg[tid], 1.f));
    if (tid < 64)
        s_r[tid] = (s_part[tid] + s_part[64 + tid] + s_part[128 + tid] + s_part[192 + tid]) * 0.02f;
    __syncthreads();
    // ---- scale adjacency: Ã[d][s] = rsI[d] * ew_sum * rsO[s]
    for (int i = tid; i < 4096; i += 256){
        int d = i >> 6, s = i & 63;
        s_A[d * 68 + s] *= s_rs[64 + d] * s_rs[s];
    }
    __syncthreads();
    // ---- extract Ã A-frags (identical in all waves; reused by conv1 & conv2)
    short8 afr[4][2];
    #pragma unroll
    for (int rt = 0; rt < 4; ++rt)
        #pragma unroll
        for (int ki = 0; ki < 2; ++ki){
            int row = rt * 16 + lnlo, k0 = ki * 32 + lghi * 8;
            float4 f0 = *(const float4*)&s_A[row * 68 + k0];
            float4 f1 = *(const float4*)&s_A[row * 68 + k0 + 4];
            short8 sv;
            sv[0] = (short)f2bf(f0.x); sv[1] = (short)f2bf(f0.y);
            sv[2] = (short)f2bf(f0.z); sv[3] = (short)f2bf(f0.w);
            sv[4] = (short)f2bf(f1.x); sv[5] = (short)f2bf(f1.y);
            sv[6] = (short)f2bf(f1.z); sv[7] = (short)f2bf(f1.w);
            afr[rt][ki] = sv;
        }
    // ---- conv1: G1 = Ã @ feat (wave wv owns cols wv*16..+15)
    f32x4 cacc[4];
    #pragma unroll
    for (int rt = 0; rt < 4; ++rt) cacc[rt] = (f32x4){0.f, 0.f, 0.f, 0.f};
    {
        short8 fb0 = *(const short8*)&s_fB[((wv * 2 + 0) * 64 + lane) * 8];
        short8 fb1 = *(const short8*)&s_fB[((wv * 2 + 1) * 64 + lane) * 8];
        #pragma unroll
        for (int rt = 0; rt < 4; ++rt){
            cacc[rt] = __builtin_amdgcn_mfma_f32_16x16x32_bf16(afr[rt][0], fb0, cacc[rt], 0, 0, 0);
            cacc[rt] = __builtin_amdgcn_mfma_f32_16x16x32_bf16(afr[rt][1], fb1, cacc[rt], 0, 0, 0);
        }
    }
    // write G1 to swizzled bf16 [64 rows][144B]
    #pragma unroll
    for (int rt = 0; rt < 4; ++rt)
        #pragma unroll
        for (int e = 0; e < 4; ++e){
            int row = rt * 16 + lghi * 4 + e;
            int col = wv * 16 + lnlo;
            *(ushort*)(s_G1 + row * 144 + ((col * 2) ^ ((row & 7) << 4))) = f2bf(cacc[rt][e]);
        }
    __syncthreads();

    // ---- GEMM1 (X1 = G1 @ W1) + norm + lrelu -> h1 halves; GEMM2 accumulates Z
    f32x4 zacc[4];
    #pragma unroll
    for (int rt = 0; rt < 4; ++rt) zacc[rt] = (f32x4){0.f, 0.f, 0.f, 0.f};

    for (int h = 0; h < 2; ++h){
        // G1 A-frags
        short8 ga[4][2];
        #pragma unroll
        for (int rt = 0; rt < 4; ++rt)
            #pragma unroll
            for (int ki = 0; ki < 2; ++ki){
                int row = rt * 16 + lnlo, k0 = ki * 32 + lghi * 8;
                ga[rt][ki] = *(const short8*)(s_G1 + row * 144 + ((k0 * 2) ^ ((row & 7) << 4)));
            }
        #pragma unroll
        for (int ctl = 0; ctl < 2; ++ctl){
            int ctg = h * 8 + wv * 2 + ctl;
            short8 wb0 = *(const short8*)&W1s[((ctg * 2 + 0) * 64 + lane) * 8];
            short8 wb1 = *(const short8*)&W1s[((ctg * 2 + 1) * 64 + lane) * 8];
            f32x4 m[4];
            #pragma unroll
            for (int rt = 0; rt < 4; ++rt) m[rt] = (f32x4){0.f, 0.f, 0.f, 0.f};
            #pragma unroll
            for (int rt = 0; rt < 4; ++rt){
                m[rt] = __builtin_amdgcn_mfma_f32_16x16x32_bf16(ga[rt][0], wb0, m[rt], 0, 0, 0);
                m[rt] = __builtin_amdgcn_mfma_f32_16x16x32_bf16(ga[rt][1], wb1, m[rt], 0, 0, 0);
            }
            // graph_norm stats (rows>=50 are exact zeros)
            float s1 = 0.f, s2 = 0.f;
            #pragma unroll
            for (int rt = 0; rt < 4; ++rt)
                #pragma unroll
                for (int e = 0; e < 4; ++e){ float x = m[rt][e]; s1 += x; s2 += x * x; }
            s1 += __shfl_xor(s1, 16); s1 += __shfl_xor(s1, 32);
            s2 += __shfl_xor(s2, 16); s2 += __shfl_xor(s2, 32);
            float mu = s1 * 0.02f;
            float var = s2 * 0.02f - mu * mu;
            float rinv = rsqrtf(var + EPSV);
            int jg = ctg * 16 + lnlo;
            float sc = g1[jg] * rinv;
            float sh = b1[jg] - mu * sc;
            float r1p = 0.f;
            int jl = (wv * 2 + ctl) * 16 + lnlo;   // local col in half
            #pragma unroll
            for (int rt = 0; rt < 4; ++rt)
                #pragma unroll
                for (int e = 0; e < 4; ++e){
                    int row = rt * 16 + lghi * 4 + e;
                    float y = m[rt][e] * sc + sh;
                    float hh = (y >= 0.f) ? y : 0.01f * y;
                    hh = (row < NP_N) ? hh : 0.f;
                    r1p += hh;
                    *(ushort*)(s_h1 + row * 272 + ((jl * 2) ^ ((row & 7) << 4))) = f2bf(hh);
                }
            r1p += __shfl_xor(r1p, 16); r1p += __shfl_xor(r1p, 32);
            if (lghi == 0) s_r[64 + jg] = r1p * 0.02f;
        }
        __syncthreads();
        // GEMM2 partial: Z += h1_half @ W2[k-slice]
        #pragma unroll
        for (int kil = 0; kil < 4; ++kil){
            short8 wb2 = *(const short8*)&W2s[((wv * 8 + h * 4 + kil) * 64 + lane) * 8];
            #pragma unroll
            for (int rt = 0; rt < 4; ++rt){
                int row = rt * 16 + lnlo, kl = kil * 32 + lghi * 8;
                short8 a = *(const short8*)(s_h1 + row * 272 + ((kl * 2) ^ ((row & 7) << 4)));
                zacc[rt] = __builtin_amdgcn_mfma_f32_16x16x32_bf16(a, wb2, zacc[rt], 0, 0, 0);
            }
        }
        __syncthreads();
    }

    // ---- write Z into B-frag layout for conv2
    #pragma unroll
    for (int rt = 0; rt < 4; ++rt)
        #pragma unroll
        for (int e = 0; e < 4; ++e){
            int row = rt * 16 + lghi * 4 + e;           // node s
            int ki2 = row >> 5, ag2 = (row & 31) >> 3, j2 = row & 7;
            s_ZB[((wv * 2 + ki2) * 64 + ag2 * 16 + lnlo) * 8 + j2] = f2bf(zacc[rt][e]);
        }
    __syncthreads();
    // ---- conv2: out = Ã @ Z (reuse afr)
    f32x4 oacc[4];
    #pragma unroll
    for (int rt = 0; rt < 4; ++rt) oacc[rt] = (f32x4){0.f, 0.f, 0.f, 0.f};
    {
        short8 zb0 = *(const short8*)&s_ZB[((wv * 2 + 0) * 64 + lane) * 8];
        short8 zb1 = *(const short8*)&s_ZB[((wv * 2 + 1) * 64 + lane) * 8];
        #pragma unroll
        for (int rt = 0; rt < 4; ++rt){
            oacc[rt] = __builtin_amdgcn_mfma_f32_16x16x32_bf16(afr[rt][0], zb0, oacc[rt], 0, 0, 0);
            oacc[rt] = __builtin_amdgcn_mfma_f32_16x16x32_bf16(afr[rt][1], zb1, oacc[rt], 0, 0, 0);
        }
    }
    // ---- norm2 + lrelu + r2 straight from accumulators
    {
        float s1 = 0.f, s2 = 0.f;
        #pragma unroll
        for (int rt = 0; rt < 4; ++rt)
            #pragma unroll
            for (int e = 0; e < 4; ++e){ float x = oacc[rt][e]; s1 += x; s2 += x * x; }
        s1 += __shfl_xor(s1, 16); s1 += __shfl_xor(s1, 32);
        s2 += __shfl_xor(s2, 16); s2 += __shfl_xor(s2, 32);
        float mu = s1 * 0.02f;
        float var = s2 * 0.02f - mu * mu;
        float rinv = rsqrtf(var + EPSV);
        int c2 = wv * 16 + lnlo;
        float sc = g2[c2] * rinv;
        float sh = b2[c2] - mu * sc;
        float r2p = 0.f;
        #pragma unroll
        for (int rt = 0; rt < 4; ++rt)
            #pragma unroll
            for (int e = 0; e < 4; ++e){
                int row = rt * 16 + lghi * 4 + e;
                float y = oacc[rt][e] * sc + sh;
                float hh = (y >= 0.f) ? y : 0.01f * y;
                r2p += (row < NP_N) ? hh : 0.f;
            }
        r2p += __shfl_xor(r2p, 16); r2p += __shfl_xor(r2p, 32);
        if (lghi == 0) s_r[320 + c2] = r2p * 0.02f;
    }
    __syncthreads();
    // ---- emb = r @ We, InstanceNorm + lrelu
    {
        int o = tid & 127, half = tid >> 7;
        float acc = 0.f;
        for (int i = half * 192; i < half * 192 + 192; ++i)
            acc = fmaf(s_r[i], We[i * 128 + o], acc);
        s_part[tid] = acc;
    }
    __syncthreads();
    float v = 0.f;
    if (tid < 128) v = s_part[tid] + s_part[tid + 128];
    float s1 = (tid < 128) ? v : 0.f;
    float s2 = s1 * s1;
    #pragma unroll
    for (int m = 32; m; m >>= 1){ s1 += __shfl_xor(s1, m); s2 += __shfl_xor(s2, m); }
    if (lane == 0 && wv < 2){ s_red[wv * 2] = s1; s_red[wv * 2 + 1] = s2; }
    __syncthreads();
    if (tid < 128){
        float T1 = s_red[0] + s_red[2], T2 = s_red[1] + s_red[3];
        float mu = T1 * (1.f / 128.f), var = T2 * (1.f / 128.f) - mu * mu;
        float y = (v - mu) * rsqrtf(var + EPSV);
        embout[(size_t)p * 128 + tid] = (y >= 0.f) ? y : 0.01f * y;
    }
}

// ---------------------------------------------------------------------------
// Mesh: degrees + CSR build
// ---------------------------------------------------------------------------
__global__ __launch_bounds__(256) void deg_kernel(
    const int* __restrict__ msrc, const int* __restrict__ mdst,
    float* __restrict__ degO, float* __restrict__ degI, int* __restrict__ cnt)
{
    int e = blockIdx.x * 256 + threadIdx.x;
    if (e < EM_N){
        int s = msrc[e], d = mdst[e];
        atomicAdd(&degO[s], 1.f);
        atomicAdd(&degI[d], 1.f);
        atomicAdd(&cnt[d], 1);
    }
}

__global__ __launch_bounds__(256) void scan_kernel(
    const int* __restrict__ cnt, int* __restrict__ offs)
{
    __shared__ int s_sc[256];
    int t = threadIdx.x;
    int sum = 0;
    for (int k = 0; k < 40; ++k){ int i = t*40 + k; if (i < PM) sum += cnt[i]; }
    s_sc[t] = sum;
    __syncthreads();
    for (int off = 1; off < 256; off <<= 1){
        int v = (t >= off) ? s_sc[t - off] : 0;
        __syncthreads();
        s_sc[t] += v;
        __syncthreads();
    }
    int run = s_sc[t] - sum;   // exclusive
    for (int k = 0; k < 40; ++k){
        int i = t*40 + k;
        if (i < PM){ offs[i] = run; run += cnt[i]; }
    }
    if (t == 255) offs[PM] = s_sc[255];
}

__global__ __launch_bounds__(256) void fill_kernel(
    const int* __restrict__ msrc, const int* __restrict__ mdst,
    const float* __restrict__ mew, const float* __restrict__ degO,
    const int* __restrict__ offs, int* __restrict__ cur,
    int* __restrict__ csrc, float* __restrict__ csw)
{
    int e = blockIdx.x * 256 + threadIdx.x;
    if (e < EM_N){
        int d = mdst[e], s = msrc[e];
        int pos = atomicAdd(&cur[d], 1);
        int idx = offs[d] + pos;
        csrc[idx] = s;
        csw[idx] = mew[e] * rsqrtf(fmaxf(degO[s], 1.f));
    }
}

// gather conv1: emb [PM][128] f32 -> agg1T [128][PM], rsI folded
__global__ __launch_bounds__(256) void gather1_kernel(
    const float* __restrict__ emb, const int* __restrict__ offs,
    const int* __restrict__ csrc, const float* __restrict__ csw,
    const float* __restrict__ degI, float* __restrict__ aggT)
{
    int lane = threadIdx.x & 63, w = threadIdx.x >> 6;
    int d = blockIdx.x * 64 + lane;
    float acc[32];
    #pragma unroll
    for (int j = 0; j < 32; ++j) acc[j] = 0.f;
    if (d < PM){
        int e0 = offs[d], e1 = offs[d+1];
        for (int i = e0; i < e1; ++i){
            int s = csrc[i]; float wt = csw[i];
            const float* src = emb + (size_t)s * 128 + w * 32;
            #pragma unroll
            for (int j4 = 0; j4 < 8; ++j4){
                float4 vv = *(const float4*)(src + j4*4);
                acc[j4*4+0] = fmaf(vv.x, wt, acc[j4*4+0]);
                acc[j4*4+1] = fmaf(vv.y, wt, acc[j4*4+1]);
                acc[j4*4+2] = fmaf(vv.z, wt, acc[j4*4+2]);
                acc[j4*4+3] = fmaf(vv.w, wt, acc[j4*4+3]);
            }
        }
        float rs = rsqrtf(fmaxf(degI[d], 1.f));
        #pragma unroll
        for (int j = 0; j < 32; ++j) aggT[(size_t)(w*32 + j) * PM + d] = acc[j] * rs;
    }
}

// gather conv2: hRow [PM][256] bf16 -> agg2T [256][PM], rsI folded
__global__ __launch_bounds__(256) void gather2_kernel(
    const ushort* __restrict__ hRow, const int* __restrict__ offs,
    const int* __restrict__ csrc, const float* __restrict__ csw,
    const float* __restrict__ degI, float* __restrict__ aggT)
{
    int lane = threadIdx.x & 63, w = threadIdx.x >> 6;
    int d = blockIdx.x * 64 + lane;
    float acc[64];
    #pragma unroll
    for (int j = 0; j < 64; ++j) acc[j] = 0.f;
    if (d < PM){
        int e0 = offs[d], e1 = offs[d+1];
        for (int i = e0; i < e1; ++i){
            int s = csrc[i]; float wt = csw[i];
            const ushort* src = hRow + (size_t)s * 256 + w * 64;
            #pragma unroll
            for (int q4 = 0; q4 < 8; ++q4){
                uint4 qv = *(const uint4*)(src + q4*8);
                unsigned u;
                u = qv.x;
                acc[q4*8+0] = fmaf(__uint_as_float(u << 16), wt, acc[q4*8+0]);
                acc[q4*8+1] = fmaf(__uint_as_float(u & 0xffff0000u), wt, acc[q4*8+1]);
                u = qv.y;
                acc[q4*8+2] = fmaf(__uint_as_float(u << 16), wt, acc[q4*8+2]);
                acc[q4*8+3] = fmaf(__uint_as_float(u & 0xffff0000u), wt, acc[q4*8+3]);
                u = qv.z;
                acc[q4*8+4] = fmaf(__uint_as_float(u << 16), wt, acc[q4*8+4]);
                acc[q4*8+5] = fmaf(__uint_as_float(u & 0xffff0000u), wt, acc[q4*8+5]);
                u = qv.w;
                acc[q4*8+6] = fmaf(__uint_as_float(u << 16), wt, acc[q4*8+6]);
                acc[q4*8+7] = fmaf(__uint_as_float(u & 0xffff0000u), wt, acc[q4*8+7]);
            }
        }
        float rs = rsqrtf(fmaxf(degI[d], 1.f));
        #pragma unroll
        for (int j = 0; j < 64; ++j) aggT[(size_t)(w*64 + j) * PM + d] = acc[j] * rs;
    }
}

// XT[j][row] = sum_c AT[c][row] * W[c][j];  N=256 out cols
__global__ __launch_bounds__(256) void mesh_gemm_kernel(
    const float* __restrict__ AT, const float* __restrict__ W,
    float* __restrict__ XT, int K)
{
    const int tid = threadIdx.x, lane = tid & 63, wave = tid >> 6;
    const int row = blockIdx.x * 64 + lane;
    const bool act = row < PM;
    const int rowc = act ? row : (PM - 1);
    const int j0 = __builtin_amdgcn_readfirstlane((blockIdx.y * 4 + wave) * 16);
    float a[16];
    #pragma unroll
    for (int jj = 0; jj < 16; ++jj) a[jj] = 0.f;
    for (int c = 0; c < K; ++c){
        float g = AT[(size_t)c * PM + rowc];
        g = act ? g : 0.f;
        const float* wp = W + c * 256 + j0;
        #pragma unroll
        for (int jj = 0; jj < 16; ++jj) a[jj] = fmaf(g, wp[jj], a[jj]);
    }
    if (act){
        #pragma unroll
        for (int jj = 0; jj < 16; ++jj) XT[(size_t)(j0 + jj) * PM + row] = a[jj];
    }
}

__device__ __forceinline__ float block_sum2(float v1, float v2, float* s_red, float* out2)
{
    #pragma unroll
    for (int m = 32; m; m >>= 1){ v1 += __shfl_xor(v1, m); v2 += __shfl_xor(v2, m); }
    int w = threadIdx.x >> 6;
    if ((threadIdx.x & 63) == 0){ s_red[w*2] = v1; s_red[w*2+1] = v2; }
    __syncthreads();
    float t1 = s_red[0] + s_red[2] + s_red[4] + s_red[6];
    float t2 = s_red[1] + s_red[3] + s_red[5] + s_red[7];
    __syncthreads();
    *out2 = t2;
    return t1;
}

__global__ __launch_bounds__(256) void col_stats_kernel(
    const float* __restrict__ X, float* __restrict__ sums, float* __restrict__ sumsq)
{
    __shared__ float s_red[8];
    int c = blockIdx.y;
    int r = blockIdx.x * 256 + threadIdx.x;
    float v = (r < PM) ? X[(size_t)c * PM + r] : 0.f;
    float sq;
    float s = block_sum2(v, v * v, s_red, &sq);
    if (threadIdx.x == 0){ atomicAdd(&sums[c], s); atomicAdd(&sumsq[c], sq); }
}

// layer-1 norm + lrelu + transpose to row-major bf16 + readout
__global__ __launch_bounds__(256) void norm1t_kernel(
    const float* __restrict__ x1T, const float* __restrict__ sums,
    const float* __restrict__ sumsq, const float* __restrict__ g,
    const float* __restrict__ b, float* __restrict__ ro, ushort* __restrict__ hRow)
{
    __shared__ float s_tile[64][65];
    int lane = threadIdx.x & 63, wvv = threadIdx.x >> 6;
    int cg = blockIdx.y;
    int rb = blockIdx.x * 64;
    int r = rb + lane;
    for (int cc = wvv; cc < 64; cc += 4){
        int c = cg * 64 + cc;
        float mu = sums[c] * (1.f / PM);
        float var = sumsq[c] * (1.f / PM) - mu * mu;
        float sc = g[c] * rsqrtf(var + EPSV);
        float sh = b[c] - mu * sc;
        float h = 0.f;
        if (r < PM){
            float x = x1T[(size_t)c * PM + r];
            float y = sc * x + sh;
            h = (y >= 0.f) ? y : 0.01f * y;
        }
        s_tile[cc][lane] = h;
        float t = h;
        #pragma unroll
        for (int m = 32; m; m >>= 1) t += __shfl_xor(t, m);
        if (lane == 0) atomicAdd(&ro[c], t);
    }
    __syncthreads();
    for (int i = wvv; i < 64; i += 4){
        int rr = rb + i;
        if (rr < PM) hRow[(size_t)rr * 256 + cg * 64 + lane] = f2bf(s_tile[i][lane]);
    }
}

// layer-2 norm + lrelu + readout (no store)
__global__ __launch_bounds__(256) void norm2_kernel(
    const float* __restrict__ X, const float* __restrict__ sums,
    const float* __restrict__ sumsq, const float* __restrict__ g,
    const float* __restrict__ b, float* __restrict__ ro)
{
    __shared__ float s_red[8];
    int c = blockIdx.y;
    int r = blockIdx.x * 256 + threadIdx.x;
    float mu = sums[c] * (1.f / PM);
    float var = sumsq[c] * (1.f / PM) - mu * mu;
    float sc = g[c] * rsqrtf(var + EPSV);
    float h = 0.f;
    if (r < PM){
        float x = X[(size_t)c * PM + r];
        float y = sc * (x - mu) + b[c];
        h = (y >= 0.f) ? y : 0.01f * y;
    }
    float dummy;
    float s = block_sum2(h, 0.f, s_red, &dummy);
    if (threadIdx.x == 0) atomicAdd(&ro[c], s);
}

__global__ __launch_bounds__(256) void final_kernel(
    const float* __restrict__ ro, const float* __restrict__ Wcls,
    float* __restrict__ out)
{
    __shared__ float s_part[256];
    int tid = threadIdx.x;
    int o = tid & 15, seg = tid >> 4;
    float pacc = 0.f;
    for (int j = seg * 32; j < seg * 32 + 32; ++j)
        pacc = fmaf(ro[j] * (1.f / PM), Wcls[j * OUT_C + o], pacc);
    s_part[tid] = pacc;
    __syncthreads();
    if (tid < OUT_C){
        float a = 0.f;
        #pragma unroll
        for (int s = 0; s < 16; ++s) a += s_part[s * 16 + tid];
        out[tid] = a;
    }
}

extern "C" void kernel_launch(void* const* d_in, const int* in_sizes, int n_in,
                              void* d_out, int out_size, void* d_ws, size_t ws_size,
                              hipStream_t stream) {
    const float* feats = (const float*)d_in[0];
    const int*   psrc  = (const int*)d_in[1];
    const int*   pdst  = (const int*)d_in[2];
    const float* pew   = (const float*)d_in[3];
    const int*   msrc  = (const int*)d_in[4];
    const int*   mdst  = (const int*)d_in[5];
    const float* mew   = (const float*)d_in[6];
    const float* W1    = (const float*)d_in[7];
    const float* g1    = (const float*)d_in[8];
    const float* b1    = (const float*)d_in[9];
    const float* W2    = (const float*)d_in[10];
    const float* g2    = (const float*)d_in[11];
    const float* b2    = (const float*)d_in[12];
    const float* We    = (const float*)d_in[13];
    const float* Wc1   = (const float*)d_in[14];
    const float* g3    = (const float*)d_in[15];
    const float* b3    = (const float*)d_in[16];
    const float* Wc2   = (const float*)d_in[17];
    const float* g4    = (const float*)d_in[18];
    const float* b4    = (const float*)d_in[19];
    const float* Wcls  = (const float*)d_in[20];
    float* out = (float*)d_out;
    float* ws  = (float*)d_ws;

    float*  degO  = ws + OFF_DEGO;
    float*  degI  = ws + OFF_DEGI;
    int*    offs  = (int*)(ws + OFF_OFFS);
    int*    cnt   = (int*)(ws + OFF_CNT);
    int*    cur   = (int*)(ws + OFF_CUR);
    int*    csrc  = (int*)(ws + OFF_CSRC);
    float*  csw   = ws + OFF_CSRW;
    float*  sums1 = ws + OFF_STATS;
    float*  sumsq1= ws + OFF_STATS + 256;
    float*  sums2 = ws + OFF_STATS + 512;
    float*  sumsq2= ws + OFF_STATS + 768;
    float*  ro    = ws + OFF_STATS + 1024;   // [512]
    ushort* W1s   = (ushort*)(ws + OFF_W1S);
    ushort* W2s   = (ushort*)(ws + OFF_W2S);
    float*  emb   = ws + OFF_EMB;
    float*  agg1T = ws + OFF_AGG1;
    float*  x1T   = ws + OFF_X1;
    ushort* hRow  = (ushort*)(ws + OFF_HROW);
    float*  agg2T = ws + OFF_AGG2;
    float*  x2T   = ws + OFF_X2;

    hipMemsetAsync(degO, 0, 20032 * sizeof(float), stream);   // degO+degI
    hipMemsetAsync(cnt,  0, 10016 * sizeof(int), stream);
    hipMemsetAsync(cur,  0, 10016 * sizeof(int), stream);
    hipMemsetAsync(sums1,0, 1536 * sizeof(float), stream);

    prep_kernel<<<128, 256, 0, stream>>>(W1, W2, W1s, W2s);
    patch_kernel<<<PM, 256, 0, stream>>>(feats, psrc, pdst, pew,
                                         W1s, g1, b1, W2s, g2, b2, We, emb);
    deg_kernel<<<EM_N/256, 256, 0, stream>>>(msrc, mdst, degO, degI, cnt);
    scan_kernel<<<1, 256, 0, stream>>>(cnt, offs);
    fill_kernel<<<EM_N/256, 256, 0, stream>>>(msrc, mdst, mew, degO, offs, cur, csrc, csw);
    gather1_kernel<<<157, 256, 0, stream>>>(emb, offs, csrc, csw, degI, agg1T);
    mesh_gemm_kernel<<<dim3(157, 4), 256, 0, stream>>>(agg1T, Wc1, x1T, 128);
    col_stats_kernel<<<dim3(40, 256), 256, 0, stream>>>(x1T, sums1, sumsq1);
    norm1t_kernel<<<dim3(157, 4), 256, 0, stream>>>(x1T, sums1, sumsq1, g3, b3, ro, hRow);
    gather2_kernel<<<157, 256, 0, stream>>>(hRow, offs, csrc, csw, degI, agg2T);
    mesh_gemm_kernel<<<dim3(157, 4), 256, 0, stream>>>(agg2T, Wc2, x2T, 256);
    col_stats_kernel<<<dim3(40, 256), 256, 0, stream>>>(x2T, sums2, sumsq2);
    norm2_kernel<<<dim3(40, 256), 256, 0, stream>>>(x2T, sums2, sumsq2, g4, b4, ro + 256);
    final_kernel<<<1, 256, 0, stream>>>(ro, Wcls, out);
}